// Round 1
// baseline (597.057 us; speedup 1.0000x reference)
//
#include <hip/hip_runtime.h>
#include <cstdint>

#define C_DIM 768
#define NPIX  196
#define HEADS 12
#define BATCH 64
#define MTOT  (BATCH * NPIX)   // 12544

typedef __bf16 bf16_t;
typedef __bf16 bf16x8 __attribute__((ext_vector_type(8)));
typedef float  f32x4  __attribute__((ext_vector_type(4)));

typedef __attribute__((address_space(1))) void as1_void_t;
typedef __attribute__((address_space(3))) void as3_void_t;

__device__ __forceinline__ f32x4 mfma16(bf16x8 a, bf16x8 b, f32x4 c) {
    return __builtin_amdgcn_mfma_f32_16x16x32_bf16(a, b, c, 0, 0, 0);
}

// global -> LDS direct copy, 16B per lane. lds pointer must be wave-uniform;
// HW writes lane i's data at lds_base + i*16.
__device__ __forceinline__ void async_copy16(const void* g, void* lds_wave_uniform) {
    __builtin_amdgcn_global_load_lds(
        (as1_void_t*)(uintptr_t)g,
        (as3_void_t*)(uint32_t)(uintptr_t)lds_wave_uniform,
        16, 0, 0);
}

// ---------------- weight transpose + bf16 convert: src[R][Cc] f32 -> dst[Cc][R] bf16
__global__ __launch_bounds__(256)
void transpose_cvt_kernel(const float* __restrict__ src, bf16_t* __restrict__ dst,
                          int R, int Cc) {
    __shared__ float tile[32][33];
    const int tx = threadIdx.x & 31, ty = threadIdx.x >> 5;   // ty 0..7
    const int c0 = blockIdx.x * 32, r0 = blockIdx.y * 32;
    #pragma unroll
    for (int i = 0; i < 32; i += 8)
        tile[ty + i][tx] = src[(size_t)(r0 + ty + i) * Cc + c0 + tx];
    __syncthreads();
    #pragma unroll
    for (int i = 0; i < 32; i += 8)
        dst[(size_t)(c0 + ty + i) * R + r0 + tx] = (bf16_t)tile[tx][ty + i];
}

__global__ __launch_bounds__(256)
void bias_concat_kernel(const float* __restrict__ bq, const float* __restrict__ bk,
                        const float* __restrict__ bv, float* __restrict__ out) {
    int i = blockIdx.x * 256 + threadIdx.x;
    if (i < 768)       out[i] = bq[i];
    else if (i < 1536) out[i] = bk[i - 768];
    else if (i < 2304) out[i] = bv[i - 1536];
}

// ---------------- LayerNorm over C per pixel: x (b,C,H,W) f32 -> t (b*N, C) bf16
__global__ __launch_bounds__(256)
void ln_kernel(const float* __restrict__ x, const float* __restrict__ g,
               const float* __restrict__ b, bf16_t* __restrict__ t) {
    const int wave = threadIdx.x >> 6, lane = threadIdx.x & 63;
    const int pg = blockIdx.x * 4 + wave;          // 12544 pixels
    const int bb = pg / NPIX, n = pg - bb * NPIX;
    const float* xp = x + (size_t)bb * C_DIM * NPIX + n;
    float vals[12], s = 0.f, s2 = 0.f;
    #pragma unroll
    for (int j = 0; j < 12; ++j) {
        float v = xp[(size_t)(j * 64 + lane) * NPIX];
        vals[j] = v; s += v; s2 += v * v;
    }
    #pragma unroll
    for (int m = 32; m; m >>= 1) { s += __shfl_xor(s, m); s2 += __shfl_xor(s2, m); }
    const float mu = s * (1.f / 768.f);
    const float var = s2 * (1.f / 768.f) - mu * mu;
    const float rs = rsqrtf(var + 1e-5f);
    bf16_t* tp = t + (size_t)pg * C_DIM;
    #pragma unroll
    for (int j = 0; j < 12; ++j) {
        int c = j * 64 + lane;
        tp[c] = (bf16_t)((vals[j] - mu) * rs * g[c] + b[c]);
    }
}

// ---------------- GEMM: C[M][Nn] = A[M][K] * Bt[Nn][K]^T, bf16 in, f32 acc
// MODE 0: QKV scatter (+bias)   MODE 1: proj (+bo +x residual -> y1f32_bchw, y1bf16)
// MODE 2: MLP1 (+b1, GELU -> h1 bf16)   MODE 3: MLP2 (+b2 +y1 -> d_out f32 bchw)
#define BM 128
#define BN 128
#define BK 64

template<int MODE>
__global__ __launch_bounds__(256)
void gemm_k(const bf16_t* __restrict__ A, const bf16_t* __restrict__ Bt,
            int M, int Nn, int K,
            const float* __restrict__ bias,
            const float* __restrict__ aux0, float* __restrict__ aux1,
            bf16_t* __restrict__ ob0, bf16_t* __restrict__ ob1, bf16_t* __restrict__ ob2)
{
    __shared__ __align__(16) char smem[(BM + BN) * BK * 2];   // 32 KB
    char* As = smem;
    char* Bs = smem + BM * BK * 2;
    const int tid = threadIdx.x;
    const int wave = tid >> 6, lane = tid & 63;
    const int lr = lane & 15, lq = lane >> 4;
    const int n0 = blockIdx.x * BN, m0 = blockIdx.y * BM;
    const int wr = (wave >> 1) * 64, wc = (wave & 1) * 64;
    const int srow = tid >> 3;                               // 0..31
    const int skx = (((tid & 7) ^ (srow & 7)) << 3);         // swizzled k-slot (elements)

    f32x4 acc[4][4];
    #pragma unroll
    for (int i = 0; i < 4; ++i)
        #pragma unroll
        for (int j = 0; j < 4; ++j)
            acc[i][j] = f32x4{0.f, 0.f, 0.f, 0.f};

    for (int k0 = 0; k0 < K; k0 += BK) {
        #pragma unroll
        for (int it = 0; it < 4; ++it) {
            int row = it * 32 + srow;
            async_copy16(A + (size_t)(m0 + row) * K + (k0 + skx),
                         As + ((it * 256 + wave * 64) << 4));
        }
        #pragma unroll
        for (int it = 0; it < 4; ++it) {
            int row = it * 32 + srow;
            async_copy16(Bt + (size_t)(n0 + row) * K + (k0 + skx),
                         Bs + ((it * 256 + wave * 64) << 4));
        }
        __syncthreads();
        #pragma unroll
        for (int ks = 0; ks < 2; ++ks) {
            bf16x8 af[4], bfv[4];
            #pragma unroll
            for (int i = 0; i < 4; ++i) {
                int row = wr + i * 16 + lr;
                int inner = (ks * 64 + lq * 16) ^ ((row & 7) << 4);
                af[i] = *(const bf16x8*)(As + row * 128 + inner);
            }
            #pragma unroll
            for (int j = 0; j < 4; ++j) {
                int row = wc + j * 16 + lr;
                int inner = (ks * 64 + lq * 16) ^ ((row & 7) << 4);
                bfv[j] = *(const bf16x8*)(Bs + row * 128 + inner);
            }
            #pragma unroll
            for (int i = 0; i < 4; ++i)
                #pragma unroll
                for (int j = 0; j < 4; ++j)
                    acc[i][j] = mfma16(af[i], bfv[j], acc[i][j]);
        }
        __syncthreads();
    }

    // ---- epilogues. C/D layout: col = lane&15 (n), row = lq*4 + reg (m).
    if constexpr (MODE == 0) {          // QKV scatter: q/k/v [b][head][n][d] bf16
        #pragma unroll
        for (int i = 0; i < 4; ++i) {
            const int grow0 = m0 + wr + i * 16 + lq * 4;
            #pragma unroll
            for (int j = 0; j < 4; ++j) {
                const int gcol = n0 + wc + j * 16 + lr;
                const int which = (gcol >= 1536) ? 2 : (gcol >= 768 ? 1 : 0);
                const int rem = gcol - which * 768;
                const int head = rem >> 6, dd = rem & 63;
                bf16_t* dst = which == 0 ? ob0 : (which == 1 ? ob1 : ob2);
                const float bval = bias[gcol];
                #pragma unroll
                for (int r = 0; r < 4; ++r) {
                    int grow = grow0 + r;
                    int bb = grow / NPIX, pix = grow - bb * NPIX;
                    dst[((size_t)(bb * HEADS + head) * NPIX + pix) * 64 + dd] =
                        (bf16_t)(acc[i][j][r] + bval);
                }
            }
        }
    } else if constexpr (MODE == 1) {   // proj: + bo + x -> y1 f32 bchw (aux1), y1 bf16 (ob0)
        #pragma unroll
        for (int i = 0; i < 4; ++i) {
            const int grow0 = m0 + wr + i * 16 + lq * 4;
            const int bb = grow0 / NPIX, pix0 = grow0 - bb * NPIX;
            #pragma unroll
            for (int j = 0; j < 4; ++j) {
                const int gcol = n0 + wc + j * 16 + lr;
                const float bval = bias[gcol];
                if (pix0 <= NPIX - 4) {
                    const size_t base = ((size_t)bb * C_DIM + gcol) * NPIX + pix0;
                    float4 xv = *(const float4*)(aux0 + base);
                    float o0 = acc[i][j][0] + bval + xv.x;
                    float o1 = acc[i][j][1] + bval + xv.y;
                    float o2 = acc[i][j][2] + bval + xv.z;
                    float o3 = acc[i][j][3] + bval + xv.w;
                    float4 ov; ov.x = o0; ov.y = o1; ov.z = o2; ov.w = o3;
                    *(float4*)(aux1 + base) = ov;
                    bf16_t* ob = ob0 + (size_t)grow0 * Nn + gcol;
                    ob[0] = (bf16_t)o0; ob[(size_t)Nn] = (bf16_t)o1;
                    ob[(size_t)2 * Nn] = (bf16_t)o2; ob[(size_t)3 * Nn] = (bf16_t)o3;
                } else {
                    #pragma unroll
                    for (int r = 0; r < 4; ++r) {
                        int grow = grow0 + r;
                        int b3 = grow / NPIX, pix = grow - b3 * NPIX;
                        size_t idx = ((size_t)b3 * C_DIM + gcol) * NPIX + pix;
                        float o = acc[i][j][r] + bval + aux0[idx];
                        aux1[idx] = o;
                        ob0[(size_t)grow * Nn + gcol] = (bf16_t)o;
                    }
                }
            }
        }
    } else if constexpr (MODE == 2) {   // MLP1: + b1, exact GELU -> h1 bf16
        #pragma unroll
        for (int i = 0; i < 4; ++i) {
            const int grow0 = m0 + wr + i * 16 + lq * 4;
            #pragma unroll
            for (int j = 0; j < 4; ++j) {
                const int gcol = n0 + wc + j * 16 + lr;
                const float bval = bias[gcol];
                #pragma unroll
                for (int r = 0; r < 4; ++r) {
                    float v = acc[i][j][r] + bval;
                    float ge = 0.5f * v * (1.f + erff(v * 0.70710678118654752f));
                    ob0[(size_t)(grow0 + r) * Nn + gcol] = (bf16_t)ge;
                }
            }
        }
    } else {                            // MLP2: + b2 + y1(aux0) -> d_out(aux1) f32 bchw
        #pragma unroll
        for (int i = 0; i < 4; ++i) {
            const int grow0 = m0 + wr + i * 16 + lq * 4;
            const int bb = grow0 / NPIX, pix0 = grow0 - bb * NPIX;
            #pragma unroll
            for (int j = 0; j < 4; ++j) {
                const int gcol = n0 + wc + j * 16 + lr;
                const float bval = bias[gcol];
                if (pix0 <= NPIX - 4) {
                    const size_t base = ((size_t)bb * C_DIM + gcol) * NPIX + pix0;
                    float4 yv = *(const float4*)(aux0 + base);
                    float4 ov;
                    ov.x = acc[i][j][0] + bval + yv.x;
                    ov.y = acc[i][j][1] + bval + yv.y;
                    ov.z = acc[i][j][2] + bval + yv.z;
                    ov.w = acc[i][j][3] + bval + yv.w;
                    *(float4*)(aux1 + base) = ov;
                } else {
                    #pragma unroll
                    for (int r = 0; r < 4; ++r) {
                        int grow = grow0 + r;
                        int b3 = grow / NPIX, pix = grow - b3 * NPIX;
                        size_t idx = ((size_t)b3 * C_DIM + gcol) * NPIX + pix;
                        aux1[idx] = acc[i][j][r] + bval + aux0[idx];
                    }
                }
            }
        }
    }
}

// ---------------- attention: one block (256 thr / 4 waves) per (b, head)
__global__ __launch_bounds__(256)
void attn_kernel(const bf16_t* __restrict__ q, const bf16_t* __restrict__ k,
                 const bf16_t* __restrict__ v, const float* __restrict__ rel_bias,
                 bf16_t* __restrict__ out)   // out: [b*196][768] bf16
{
    __shared__ __align__(16) bf16_t VT[64][232];      // V transposed, cols padded/zeroed to 224
    __shared__ __align__(16) bf16_t P[4][16][256];    // per-wave P, 16B-slot XOR swizzle
    __shared__ float btab[736];
    const int tid = threadIdx.x, wave = tid >> 6, lane = tid & 63;
    const int lr = lane & 15, lq = lane >> 4;
    const int bh = blockIdx.x;
    const int bb = bh / HEADS, hh = bh - bb * HEADS;

    for (int i = tid; i < 729; i += 256) btab[i] = rel_bias[hh * 729 + i];
    const bf16_t* vbase = v + (size_t)bh * NPIX * 64;
    for (int idx = tid; idx < NPIX * 64; idx += 256)
        VT[idx & 63][idx >> 6] = vbase[idx];
    for (int idx = tid; idx < 64 * 28; idx += 256)
        VT[idx & 63][NPIX + (idx >> 6)] = (bf16_t)0.f;
    {   // zero P logical cols 208..223 (k-padding), all 16 rows
        int row = lr;
        #pragma unroll
        for (int cc = 0; cc < 4; ++cc) {
            int col = 208 + lq + cc * 4;
            int slot = (col >> 3) ^ (row & 7);
            P[wave][row][slot * 8 + (col & 7)] = (bf16_t)0.f;
        }
    }
    __syncthreads();

    const bf16_t* qb = q + (size_t)bh * NPIX * 64;
    const bf16_t* kb = k + (size_t)bh * NPIX * 64;

    for (int rt = wave; rt < 13; rt += 4) {
        bf16x8 qf0 = *(const bf16x8*)(qb + (rt * 16 + lr) * 64 + lq * 8);
        bf16x8 qf1 = *(const bf16x8*)(qb + (rt * 16 + lr) * 64 + 32 + lq * 8);
        f32x4 acc[13];
        const int nrow0 = rt * 16 + lq * 4;
        #pragma unroll
        for (int ct = 0; ct < 13; ++ct) {
            #pragma unroll
            for (int r = 0; r < 4; ++r) {
                const int n = nrow0 + r;       // query index (may be >=196: unused rows)
                const int m = ct * 16 + lr;    // key index
                float init;
                if (m < NPIX) {
                    int pyn = n / 14, pxn = n - pyn * 14;
                    int pym = m / 14, pxm = m - pym * 14;
                    init = btab[(pym - pyn + 14) * 14 + (pxm - pxn + 14)];
                } else init = -1e30f;
                acc[ct][r] = init;
            }
        }
        #pragma unroll
        for (int ct = 0; ct < 13; ++ct) {
            const bf16_t* kr = kb + (ct * 16 + lr) * 64 + lq * 8;
            bf16x8 kf0 = *(const bf16x8*)(kr);
            bf16x8 kf1 = *(const bf16x8*)(kr + 32);
            acc[ct] = mfma16(qf0, kf0, acc[ct]);
            acc[ct] = mfma16(qf1, kf1, acc[ct]);
        }
        // softmax (row = query lives in 16 lanes sharing lq; reduce over lane&15)
        #pragma unroll
        for (int r = 0; r < 4; ++r) {
            float mx = -1e30f;
            #pragma unroll
            for (int ct = 0; ct < 13; ++ct) mx = fmaxf(mx, acc[ct][r]);
            #pragma unroll
            for (int s = 1; s < 16; s <<= 1) mx = fmaxf(mx, __shfl_xor(mx, s));
            float sum = 0.f;
            #pragma unroll
            for (int ct = 0; ct < 13; ++ct) {
                float e = __expf(acc[ct][r] - mx);
                acc[ct][r] = e; sum += e;
            }
            #pragma unroll
            for (int s = 1; s < 16; s <<= 1) sum += __shfl_xor(sum, s);
            float inv = 1.f / sum;
            #pragma unroll
            for (int ct = 0; ct < 13; ++ct) acc[ct][r] *= inv;
        }
        // P -> LDS (swizzled 16B slots)
        #pragma unroll
        for (int ct = 0; ct < 13; ++ct) {
            #pragma unroll
            for (int r = 0; r < 4; ++r) {
                int row = lq * 4 + r;
                int col = ct * 16 + lr;
                int slot = (col >> 3) ^ (row & 7);
                P[wave][row][slot * 8 + (col & 7)] = (bf16_t)acc[ct][r];
            }
        }
        // PV
        f32x4 accO[4];
        #pragma unroll
        for (int dt = 0; dt < 4; ++dt) accO[dt] = f32x4{0.f, 0.f, 0.f, 0.f};
        #pragma unroll
        for (int ks = 0; ks < 7; ++ks) {
            int kk = ks * 32 + lq * 8;
            int slot = (kk >> 3) ^ (lr & 7);
            bf16x8 pa = *(const bf16x8*)(&P[wave][lr][slot * 8]);
            #pragma unroll
            for (int dt = 0; dt < 4; ++dt) {
                bf16x8 vb2 = *(const bf16x8*)(&VT[dt * 16 + lr][kk]);
                accO[dt] = mfma16(pa, vb2, accO[dt]);
            }
        }
        // write out rows < 196
        #pragma unroll
        for (int dt = 0; dt < 4; ++dt) {
            #pragma unroll
            for (int r = 0; r < 4; ++r) {
                int n = nrow0 + r;
                if (n < NPIX)
                    out[((size_t)bb * NPIX + n) * C_DIM + hh * 64 + dt * 16 + lr] =
                        (bf16_t)accO[dt][r];
            }
        }
    }
}

extern "C" void kernel_launch(void* const* d_in, const int* in_sizes, int n_in,
                              void* d_out, int out_size, void* d_ws, size_t ws_size,
                              hipStream_t stream) {
    const float* x    = (const float*)d_in[0];
    const float* ln_g = (const float*)d_in[1];
    const float* ln_b = (const float*)d_in[2];
    const float* wq   = (const float*)d_in[3];
    const float* bq   = (const float*)d_in[4];
    const float* wk   = (const float*)d_in[5];
    const float* bk   = (const float*)d_in[6];
    const float* wv   = (const float*)d_in[7];
    const float* bv   = (const float*)d_in[8];
    const float* wo   = (const float*)d_in[9];
    const float* bo   = (const float*)d_in[10];
    const float* w1   = (const float*)d_in[11];
    const float* b1   = (const float*)d_in[12];
    const float* w2   = (const float*)d_in[13];
    const float* b2   = (const float*)d_in[14];
    const float* rb   = (const float*)d_in[15];

    char* ws = (char*)d_ws;
    size_t off = 0;
    auto carve = [&](size_t bytes) -> char* {
        char* p = ws + off;
        off += (bytes + 255) & ~(size_t)255;
        return p;
    };
    const size_t SZROW = (size_t)MTOT * C_DIM * 2;            // 19,267,584 B
    bf16_t* wqkvT = (bf16_t*)carve((size_t)2304 * 768 * 2);
    bf16_t* woT   = (bf16_t*)carve((size_t)768 * 768 * 2);
    bf16_t* w1T   = (bf16_t*)carve((size_t)3072 * 768 * 2);
    bf16_t* w2T   = (bf16_t*)carve((size_t)768 * 3072 * 2);
    float*  bqkv  = (float*)carve(2304 * 4);
    char*   regionA = carve(4 * SZROW + 65536);               // t|q|k|v, reused as h1
    bf16_t* tbuf = (bf16_t*)regionA;
    bf16_t* qb   = (bf16_t*)(regionA + SZROW);
    bf16_t* kb   = (bf16_t*)(regionA + 2 * SZROW);
    bf16_t* vb   = (bf16_t*)(regionA + 3 * SZROW);
    bf16_t* attn_out = tbuf;                                  // t dead after QKV
    bf16_t* h1 = (bf16_t*)regionA;                            // whole region dead after proj
    float*  y1f = (float*)carve((size_t)MTOT * C_DIM * 4);
    bf16_t* y1b = (bf16_t*)carve(SZROW);

    transpose_cvt_kernel<<<dim3(24, 24), 256, 0, stream>>>(wq, wqkvT, 768, 768);
    transpose_cvt_kernel<<<dim3(24, 24), 256, 0, stream>>>(wk, wqkvT + 768 * 768, 768, 768);
    transpose_cvt_kernel<<<dim3(24, 24), 256, 0, stream>>>(wv, wqkvT + 2 * 768 * 768, 768, 768);
    transpose_cvt_kernel<<<dim3(24, 24), 256, 0, stream>>>(wo, woT, 768, 768);
    transpose_cvt_kernel<<<dim3(96, 24), 256, 0, stream>>>(w1, w1T, 768, 3072);
    transpose_cvt_kernel<<<dim3(24, 96), 256, 0, stream>>>(w2, w2T, 3072, 768);
    bias_concat_kernel<<<9, 256, 0, stream>>>(bq, bk, bv, bqkv);
    ln_kernel<<<MTOT / 4, 256, 0, stream>>>(x, ln_g, ln_b, tbuf);
    gemm_k<0><<<dim3(18, 98), 256, 0, stream>>>(tbuf, wqkvT, MTOT, 2304, 768, bqkv,
                                                nullptr, nullptr, qb, kb, vb);
    attn_kernel<<<768, 256, 0, stream>>>(qb, kb, vb, rb, attn_out);
    gemm_k<1><<<dim3(6, 98), 256, 0, stream>>>(attn_out, woT, MTOT, 768, 768, bo,
                                               x, y1f, y1b, nullptr, nullptr);
    gemm_k<2><<<dim3(24, 98), 256, 0, stream>>>(y1b, w1T, MTOT, 3072, 768, b1,
                                                nullptr, nullptr, h1, nullptr, nullptr);
    gemm_k<3><<<dim3(6, 98), 256, 0, stream>>>(h1, w2T, MTOT, 768, 3072, b2,
                                               y1f, (float*)d_out, nullptr, nullptr, nullptr);
}

// Round 2
// 580.193 us; speedup vs baseline: 1.0291x; 1.0291x over previous
//
#include <hip/hip_runtime.h>
#include <cstdint>

#define C_DIM 768
#define NPIX  196
#define HEADS 12
#define BATCH 64
#define MTOT  (BATCH * NPIX)   // 12544

typedef __bf16 bf16_t;
typedef __bf16 bf16x8 __attribute__((ext_vector_type(8)));
typedef float  f32x4  __attribute__((ext_vector_type(4)));

typedef __attribute__((address_space(1))) void as1_void_t;
typedef __attribute__((address_space(3))) void as3_void_t;

__device__ __forceinline__ f32x4 mfma16(bf16x8 a, bf16x8 b, f32x4 c) {
    return __builtin_amdgcn_mfma_f32_16x16x32_bf16(a, b, c, 0, 0, 0);
}

__device__ __forceinline__ void async_copy16(const void* g, void* lds_wave_uniform) {
    __builtin_amdgcn_global_load_lds(
        (as1_void_t*)(uintptr_t)g,
        (as3_void_t*)(uint32_t)(uintptr_t)lds_wave_uniform,
        16, 0, 0);
}

// ---------------- merged prep: 6 weight transposes (f32->bf16, [R][C]->[C][R]) + bias concat
// tiles: t<576 wq | <1152 wk | <1728 wv | <2304 wo | <4608 w1 (768x3072) | <6912 w2 (3072x768)
// t in [6912, 6921): bias concat (2304 floats)
__global__ __launch_bounds__(256)
void prep_kernel(const float* __restrict__ wq, const float* __restrict__ wk,
                 const float* __restrict__ wv, const float* __restrict__ wo,
                 const float* __restrict__ w1, const float* __restrict__ w2,
                 const float* __restrict__ bq, const float* __restrict__ bk,
                 const float* __restrict__ bv,
                 bf16_t* __restrict__ wqkvT, bf16_t* __restrict__ woT,
                 bf16_t* __restrict__ w1T, bf16_t* __restrict__ w2T,
                 float* __restrict__ bqkv)
{
    const int t = blockIdx.x;
    if (t >= 6912) {
        int i = (t - 6912) * 256 + threadIdx.x;
        if (i < 768)       bqkv[i] = bq[i];
        else if (i < 1536) bqkv[i] = bk[i - 768];
        else if (i < 2304) bqkv[i] = bv[i - 1536];
        return;
    }
    const float* src; bf16_t* dst; int R, Cc, local;
    if (t < 2304) {
        int which = t / 576; local = t - which * 576;
        src = which == 0 ? wq : (which == 1 ? wk : (which == 2 ? wv : wo));
        dst = which == 3 ? woT : wqkvT + which * 768 * 768;
        R = 768; Cc = 768;
    } else if (t < 4608) { local = t - 2304; src = w1; dst = w1T; R = 768;  Cc = 3072; }
    else                 { local = t - 4608; src = w2; dst = w2T; R = 3072; Cc = 768;  }
    const int ntx = Cc >> 5;
    const int bx = local % ntx, by = local / ntx;
    __shared__ float tile[32][33];
    const int tx = threadIdx.x & 31, ty = threadIdx.x >> 5;
    const int c0 = bx * 32, r0 = by * 32;
    #pragma unroll
    for (int i = 0; i < 32; i += 8)
        tile[ty + i][tx] = src[(size_t)(r0 + ty + i) * Cc + c0 + tx];
    __syncthreads();
    #pragma unroll
    for (int i = 0; i < 32; i += 8)
        dst[(size_t)(c0 + ty + i) * R + r0 + tx] = (bf16_t)tile[tx][ty + i];
}

// ---------------- LayerNorm over C per pixel: x (b,C,H,W) f32 -> t (b*N, C) bf16
__global__ __launch_bounds__(256)
void ln_kernel(const float* __restrict__ x, const float* __restrict__ g,
               const float* __restrict__ b, bf16_t* __restrict__ t) {
    const int wave = threadIdx.x >> 6, lane = threadIdx.x & 63;
    const int pg = blockIdx.x * 4 + wave;
    const int bb = pg / NPIX, n = pg - bb * NPIX;
    const float* xp = x + (size_t)bb * C_DIM * NPIX + n;
    float vals[12], s = 0.f, s2 = 0.f;
    #pragma unroll
    for (int j = 0; j < 12; ++j) {
        float v = xp[(size_t)(j * 64 + lane) * NPIX];
        vals[j] = v; s += v; s2 += v * v;
    }
    #pragma unroll
    for (int m = 32; m; m >>= 1) { s += __shfl_xor(s, m); s2 += __shfl_xor(s2, m); }
    const float mu = s * (1.f / 768.f);
    const float var = s2 * (1.f / 768.f) - mu * mu;
    const float rs = rsqrtf(var + 1e-5f);
    bf16_t* tp = t + (size_t)pg * C_DIM;
    #pragma unroll
    for (int j = 0; j < 12; ++j) {
        int c = j * 64 + lane;
        tp[c] = (bf16_t)((vals[j] - mu) * rs * g[c] + b[c]);
    }
}

// ---------------- GEMM: C[M][Nn] = A[M][K] * Bt[Nn][K]^T, bf16 in, f32 acc
// MODE 0: QKV scatter (+bias)   MODE 1: proj (+bo +x residual -> y1f32_bchw, y1bf16)
// MODE 2: MLP1 (+b1, GELU -> h1 bf16)   MODE 3: MLP2 (+b2 +y1 -> d_out f32 bchw)
#define BM 128
#define BN 128
#define BK 64

template<int MODE>
__global__ __launch_bounds__(256)
void gemm_k(const bf16_t* __restrict__ A, const bf16_t* __restrict__ Bt,
            int M, int Nn, int K,
            const float* __restrict__ bias,
            const float* __restrict__ aux0, float* __restrict__ aux1,
            bf16_t* __restrict__ ob0, bf16_t* __restrict__ ob1, bf16_t* __restrict__ ob2)
{
    __shared__ __align__(16) char smem[(BM + BN) * BK * 2];   // 32 KB
    char* As = smem;
    char* Bs = smem + BM * BK * 2;
    const int tid = threadIdx.x;
    const int wave = tid >> 6, lane = tid & 63;
    const int lr = lane & 15, lq = lane >> 4;

    // XCD-chunked bijective swizzle (m204): same-A-panel blocks -> same XCD chunk.
    const int nwg = gridDim.x;
    const int orig = blockIdx.x;
    const int q8 = nwg >> 3, r8 = nwg & 7;
    const int xcd = orig & 7, slot = orig >> 3;
    const int lg = (xcd < r8 ? xcd * (q8 + 1) : r8 * (q8 + 1) + (xcd - r8) * q8) + slot;
    const int gn = Nn >> 7;                       // n-blocks (fastest) => A-panel locality
    const int nb = lg % gn, mb = lg / gn;
    const int n0 = nb * BN, m0 = mb * BM;

    const int wr = (wave >> 1) * 64, wc = (wave & 1) * 64;
    const int srow = tid >> 3;                               // 0..31
    const int skx = (((tid & 7) ^ (srow & 7)) << 3);         // swizzled k-slot (elements)

    f32x4 acc[4][4];
    #pragma unroll
    for (int i = 0; i < 4; ++i)
        #pragma unroll
        for (int j = 0; j < 4; ++j)
            acc[i][j] = f32x4{0.f, 0.f, 0.f, 0.f};

    for (int k0 = 0; k0 < K; k0 += BK) {
        #pragma unroll
        for (int it = 0; it < 4; ++it) {
            int row = it * 32 + srow;
            async_copy16(A + (size_t)(m0 + row) * K + (k0 + skx),
                         As + ((it * 256 + wave * 64) << 4));
        }
        #pragma unroll
        for (int it = 0; it < 4; ++it) {
            int row = it * 32 + srow;
            async_copy16(Bt + (size_t)(n0 + row) * K + (k0 + skx),
                         Bs + ((it * 256 + wave * 64) << 4));
        }
        __syncthreads();
        #pragma unroll
        for (int ks = 0; ks < 2; ++ks) {
            bf16x8 af[4], bfv[4];
            #pragma unroll
            for (int i = 0; i < 4; ++i) {
                int row = wr + i * 16 + lr;
                int inner = (ks * 64 + lq * 16) ^ ((row & 7) << 4);
                af[i] = *(const bf16x8*)(As + row * 128 + inner);
            }
            #pragma unroll
            for (int j = 0; j < 4; ++j) {
                int row = wc + j * 16 + lr;
                int inner = (ks * 64 + lq * 16) ^ ((row & 7) << 4);
                bfv[j] = *(const bf16x8*)(Bs + row * 128 + inner);
            }
            #pragma unroll
            for (int i = 0; i < 4; ++i)
                #pragma unroll
                for (int j = 0; j < 4; ++j)
                    acc[i][j] = mfma16(af[i], bfv[j], acc[i][j]);
        }
        __syncthreads();
    }

    // ---- epilogues. C/D layout: col = lane&15 (n), row = lq*4 + reg (m).
    if constexpr (MODE == 0) {          // QKV scatter: q/k/v [b][head][n][d] bf16
        #pragma unroll
        for (int i = 0; i < 4; ++i) {
            const int grow0 = m0 + wr + i * 16 + lq * 4;
            #pragma unroll
            for (int j = 0; j < 4; ++j) {
                const int gcol = n0 + wc + j * 16 + lr;
                const int which = (gcol >= 1536) ? 2 : (gcol >= 768 ? 1 : 0);
                const int rem = gcol - which * 768;
                const int head = rem >> 6, dd = rem & 63;
                bf16_t* dst = which == 0 ? ob0 : (which == 1 ? ob1 : ob2);
                const float bval = bias[gcol];
                #pragma unroll
                for (int r = 0; r < 4; ++r) {
                    int grow = grow0 + r;
                    int bb = grow / NPIX, pix = grow - bb * NPIX;
                    dst[((size_t)(bb * HEADS + head) * NPIX + pix) * 64 + dd] =
                        (bf16_t)(acc[i][j][r] + bval);
                }
            }
        }
    } else if constexpr (MODE == 1) {   // proj: + bo + x -> y1 f32 bchw (aux1), y1 bf16 (ob0)
        #pragma unroll
        for (int i = 0; i < 4; ++i) {
            const int grow0 = m0 + wr + i * 16 + lq * 4;
            const int bb = grow0 / NPIX, pix0 = grow0 - bb * NPIX;
            #pragma unroll
            for (int j = 0; j < 4; ++j) {
                const int gcol = n0 + wc + j * 16 + lr;
                const float bval = bias[gcol];
                if (pix0 <= NPIX - 4) {
                    const size_t base = ((size_t)bb * C_DIM + gcol) * NPIX + pix0;
                    float4 xv = *(const float4*)(aux0 + base);
                    float o0 = acc[i][j][0] + bval + xv.x;
                    float o1 = acc[i][j][1] + bval + xv.y;
                    float o2 = acc[i][j][2] + bval + xv.z;
                    float o3 = acc[i][j][3] + bval + xv.w;
                    float4 ov; ov.x = o0; ov.y = o1; ov.z = o2; ov.w = o3;
                    *(float4*)(aux1 + base) = ov;
                    bf16_t* ob = ob0 + (size_t)grow0 * Nn + gcol;
                    ob[0] = (bf16_t)o0; ob[(size_t)Nn] = (bf16_t)o1;
                    ob[(size_t)2 * Nn] = (bf16_t)o2; ob[(size_t)3 * Nn] = (bf16_t)o3;
                } else {
                    #pragma unroll
                    for (int r = 0; r < 4; ++r) {
                        int grow = grow0 + r;
                        int b3 = grow / NPIX, pix = grow - b3 * NPIX;
                        size_t idx = ((size_t)b3 * C_DIM + gcol) * NPIX + pix;
                        float o = acc[i][j][r] + bval + aux0[idx];
                        aux1[idx] = o;
                        ob0[(size_t)grow * Nn + gcol] = (bf16_t)o;
                    }
                }
            }
        }
    } else if constexpr (MODE == 2) {   // MLP1: + b1, exact GELU -> h1 bf16
        #pragma unroll
        for (int i = 0; i < 4; ++i) {
            const int grow0 = m0 + wr + i * 16 + lq * 4;
            #pragma unroll
            for (int j = 0; j < 4; ++j) {
                const int gcol = n0 + wc + j * 16 + lr;
                const float bval = bias[gcol];
                #pragma unroll
                for (int r = 0; r < 4; ++r) {
                    float v = acc[i][j][r] + bval;
                    float ge = 0.5f * v * (1.f + erff(v * 0.70710678118654752f));
                    ob0[(size_t)(grow0 + r) * Nn + gcol] = (bf16_t)ge;
                }
            }
        }
    } else {                            // MLP2: + b2 + y1(aux0) -> d_out(aux1) f32 bchw
        #pragma unroll
        for (int i = 0; i < 4; ++i) {
            const int grow0 = m0 + wr + i * 16 + lq * 4;
            const int bb = grow0 / NPIX, pix0 = grow0 - bb * NPIX;
            #pragma unroll
            for (int j = 0; j < 4; ++j) {
                const int gcol = n0 + wc + j * 16 + lr;
                const float bval = bias[gcol];
                if (pix0 <= NPIX - 4) {
                    const size_t base = ((size_t)bb * C_DIM + gcol) * NPIX + pix0;
                    float4 yv = *(const float4*)(aux0 + base);
                    float4 ov;
                    ov.x = acc[i][j][0] + bval + yv.x;
                    ov.y = acc[i][j][1] + bval + yv.y;
                    ov.z = acc[i][j][2] + bval + yv.z;
                    ov.w = acc[i][j][3] + bval + yv.w;
                    *(float4*)(aux1 + base) = ov;
                } else {
                    #pragma unroll
                    for (int r = 0; r < 4; ++r) {
                        int grow = grow0 + r;
                        int b3 = grow / NPIX, pix = grow - b3 * NPIX;
                        size_t idx = ((size_t)b3 * C_DIM + gcol) * NPIX + pix;
                        aux1[idx] = acc[i][j][r] + bval + aux0[idx];
                    }
                }
            }
        }
    }
}

// ---------------- attention: one block (256 thr / 4 waves) per (b, head)
__global__ __launch_bounds__(256)
void attn_kernel(const bf16_t* __restrict__ q, const bf16_t* __restrict__ k,
                 const bf16_t* __restrict__ v, const float* __restrict__ rel_bias,
                 bf16_t* __restrict__ out)   // out: [b*196][768] bf16
{
    __shared__ __align__(16) bf16_t VT[64][232];
    __shared__ __align__(16) bf16_t P[4][16][256];
    __shared__ float btab[736];
    const int tid = threadIdx.x, wave = tid >> 6, lane = tid & 63;
    const int lr = lane & 15, lq = lane >> 4;
    const int bh = blockIdx.x;
    const int bb = bh / HEADS, hh = bh - bb * HEADS;

    for (int i = tid; i < 729; i += 256) btab[i] = rel_bias[hh * 729 + i];
    const bf16_t* vbase = v + (size_t)bh * NPIX * 64;
    for (int idx = tid; idx < NPIX * 64; idx += 256)
        VT[idx & 63][idx >> 6] = vbase[idx];
    for (int idx = tid; idx < 64 * 28; idx += 256)
        VT[idx & 63][NPIX + (idx >> 6)] = (bf16_t)0.f;
    {
        int row = lr;
        #pragma unroll
        for (int cc = 0; cc < 4; ++cc) {
            int col = 208 + lq + cc * 4;
            int slot = (col >> 3) ^ (row & 7);
            P[wave][row][slot * 8 + (col & 7)] = (bf16_t)0.f;
        }
    }
    __syncthreads();

    const bf16_t* qb = q + (size_t)bh * NPIX * 64;
    const bf16_t* kb = k + (size_t)bh * NPIX * 64;

    for (int rt = wave; rt < 13; rt += 4) {
        bf16x8 qf0 = *(const bf16x8*)(qb + (rt * 16 + lr) * 64 + lq * 8);
        bf16x8 qf1 = *(const bf16x8*)(qb + (rt * 16 + lr) * 64 + 32 + lq * 8);
        f32x4 acc[13];
        const int nrow0 = rt * 16 + lq * 4;
        #pragma unroll
        for (int ct = 0; ct < 13; ++ct) {
            #pragma unroll
            for (int r = 0; r < 4; ++r) {
                const int n = nrow0 + r;
                const int m = ct * 16 + lr;
                float init;
                if (m < NPIX) {
                    int pyn = n / 14, pxn = n - pyn * 14;
                    int pym = m / 14, pxm = m - pym * 14;
                    init = btab[(pym - pyn + 14) * 14 + (pxm - pxn + 14)];
                } else init = -1e30f;
                acc[ct][r] = init;
            }
        }
        #pragma unroll
        for (int ct = 0; ct < 13; ++ct) {
            const bf16_t* kr = kb + (ct * 16 + lr) * 64 + lq * 8;
            bf16x8 kf0 = *(const bf16x8*)(kr);
            bf16x8 kf1 = *(const bf16x8*)(kr + 32);
            acc[ct] = mfma16(qf0, kf0, acc[ct]);
            acc[ct] = mfma16(qf1, kf1, acc[ct]);
        }
        #pragma unroll
        for (int r = 0; r < 4; ++r) {
            float mx = -1e30f;
            #pragma unroll
            for (int ct = 0; ct < 13; ++ct) mx = fmaxf(mx, acc[ct][r]);
            #pragma unroll
            for (int s = 1; s < 16; s <<= 1) mx = fmaxf(mx, __shfl_xor(mx, s));
            float sum = 0.f;
            #pragma unroll
            for (int ct = 0; ct < 13; ++ct) {
                float e = __expf(acc[ct][r] - mx);
                acc[ct][r] = e; sum += e;
            }
            #pragma unroll
            for (int s = 1; s < 16; s <<= 1) sum += __shfl_xor(sum, s);
            float inv = 1.f / sum;
            #pragma unroll
            for (int ct = 0; ct < 13; ++ct) acc[ct][r] *= inv;
        }
        #pragma unroll
        for (int ct = 0; ct < 13; ++ct) {
            #pragma unroll
            for (int r = 0; r < 4; ++r) {
                int row = lq * 4 + r;
                int col = ct * 16 + lr;
                int slot = (col >> 3) ^ (row & 7);
                P[wave][row][slot * 8 + (col & 7)] = (bf16_t)acc[ct][r];
            }
        }
        f32x4 accO[4];
        #pragma unroll
        for (int dt = 0; dt < 4; ++dt) accO[dt] = f32x4{0.f, 0.f, 0.f, 0.f};
        #pragma unroll
        for (int ks = 0; ks < 7; ++ks) {
            int kk = ks * 32 + lq * 8;
            int slot = (kk >> 3) ^ (lr & 7);
            bf16x8 pa = *(const bf16x8*)(&P[wave][lr][slot * 8]);
            #pragma unroll
            for (int dt = 0; dt < 4; ++dt) {
                bf16x8 vb2 = *(const bf16x8*)(&VT[dt * 16 + lr][kk]);
                accO[dt] = mfma16(pa, vb2, accO[dt]);
            }
        }
        #pragma unroll
        for (int dt = 0; dt < 4; ++dt) {
            #pragma unroll
            for (int r = 0; r < 4; ++r) {
                int n = nrow0 + r;
                if (n < NPIX)
                    out[((size_t)bb * NPIX + n) * C_DIM + hh * 64 + dt * 16 + lr] =
                        (bf16_t)accO[dt][r];
            }
        }
    }
}

extern "C" void kernel_launch(void* const* d_in, const int* in_sizes, int n_in,
                              void* d_out, int out_size, void* d_ws, size_t ws_size,
                              hipStream_t stream) {
    const float* x    = (const float*)d_in[0];
    const float* ln_g = (const float*)d_in[1];
    const float* ln_b = (const float*)d_in[2];
    const float* wq   = (const float*)d_in[3];
    const float* bq   = (const float*)d_in[4];
    const float* wk   = (const float*)d_in[5];
    const float* bk   = (const float*)d_in[6];
    const float* wv   = (const float*)d_in[7];
    const float* bv   = (const float*)d_in[8];
    const float* wo   = (const float*)d_in[9];
    const float* bo   = (const float*)d_in[10];
    const float* w1   = (const float*)d_in[11];
    const float* b1   = (const float*)d_in[12];
    const float* w2   = (const float*)d_in[13];
    const float* b2   = (const float*)d_in[14];
    const float* rb   = (const float*)d_in[15];

    char* ws = (char*)d_ws;
    size_t off = 0;
    auto carve = [&](size_t bytes) -> char* {
        char* p = ws + off;
        off += (bytes + 255) & ~(size_t)255;
        return p;
    };
    const size_t SZROW = (size_t)MTOT * C_DIM * 2;            // 19,267,584 B
    bf16_t* wqkvT = (bf16_t*)carve((size_t)2304 * 768 * 2);
    bf16_t* woT   = (bf16_t*)carve((size_t)768 * 768 * 2);
    bf16_t* w1T   = (bf16_t*)carve((size_t)3072 * 768 * 2);
    bf16_t* w2T   = (bf16_t*)carve((size_t)768 * 3072 * 2);
    float*  bqkv  = (float*)carve(2304 * 4);
    char*   regionA = carve(4 * SZROW + 65536);               // t|q|k|v, reused as h1
    bf16_t* tbuf = (bf16_t*)regionA;
    bf16_t* qb   = (bf16_t*)(regionA + SZROW);
    bf16_t* kb   = (bf16_t*)(regionA + 2 * SZROW);
    bf16_t* vb   = (bf16_t*)(regionA + 3 * SZROW);
    bf16_t* attn_out = tbuf;                                  // t dead after QKV
    bf16_t* h1 = (bf16_t*)regionA;                            // whole region dead after proj
    float*  y1f = (float*)carve((size_t)MTOT * C_DIM * 4);
    bf16_t* y1b = (bf16_t*)carve(SZROW);

    prep_kernel<<<6921, 256, 0, stream>>>(wq, wk, wv, wo, w1, w2, bq, bk, bv,
                                          wqkvT, woT, w1T, w2T, bqkv);
    ln_kernel<<<MTOT / 4, 256, 0, stream>>>(x, ln_g, ln_b, tbuf);
    gemm_k<0><<<18 * 98, 256, 0, stream>>>(tbuf, wqkvT, MTOT, 2304, 768, bqkv,
                                           nullptr, nullptr, qb, kb, vb);
    attn_kernel<<<768, 256, 0, stream>>>(qb, kb, vb, rb, attn_out);
    gemm_k<1><<<6 * 98, 256, 0, stream>>>(attn_out, woT, MTOT, 768, 768, bo,
                                          x, y1f, y1b, nullptr, nullptr);
    gemm_k<2><<<24 * 98, 256, 0, stream>>>(y1b, w1T, MTOT, 3072, 768, b1,
                                           nullptr, nullptr, h1, nullptr, nullptr);
    gemm_k<3><<<6 * 98, 256, 0, stream>>>(h1, w2T, MTOT, 768, 3072, b2,
                                          y1f, (float*)d_out, nullptr, nullptr, nullptr);
}

// Round 3
// 524.379 us; speedup vs baseline: 1.1386x; 1.1064x over previous
//
#include <hip/hip_runtime.h>
#include <cstdint>

#define C_DIM 768
#define NPIX  196
#define HEADS 12
#define BATCH 64
#define MTOT  (BATCH * NPIX)   // 12544

typedef __bf16 bf16_t;
typedef __bf16 bf16x8 __attribute__((ext_vector_type(8)));
typedef float  f32x4  __attribute__((ext_vector_type(4)));

typedef __attribute__((address_space(1))) void as1_void_t;
typedef __attribute__((address_space(3))) void as3_void_t;

__device__ __forceinline__ f32x4 mfma16(bf16x8 a, bf16x8 b, f32x4 c) {
    return __builtin_amdgcn_mfma_f32_16x16x32_bf16(a, b, c, 0, 0, 0);
}

__device__ __forceinline__ void async_copy16(const void* g, void* lds_wave_uniform) {
    __builtin_amdgcn_global_load_lds(
        (as1_void_t*)(uintptr_t)g,
        (as3_void_t*)(uint32_t)(uintptr_t)lds_wave_uniform,
        16, 0, 0);
}

// ---------------- merged prep: 6 weight transposes (f32->bf16, [R][C]->[C][R]) + bias concat
__global__ __launch_bounds__(256)
void prep_kernel(const float* __restrict__ wq, const float* __restrict__ wk,
                 const float* __restrict__ wv, const float* __restrict__ wo,
                 const float* __restrict__ w1, const float* __restrict__ w2,
                 const float* __restrict__ bq, const float* __restrict__ bk,
                 const float* __restrict__ bv,
                 bf16_t* __restrict__ wqkvT, bf16_t* __restrict__ woT,
                 bf16_t* __restrict__ w1T, bf16_t* __restrict__ w2T,
                 float* __restrict__ bqkv)
{
    const int t = blockIdx.x;
    if (t >= 6912) {
        int i = (t - 6912) * 256 + threadIdx.x;
        if (i < 768)       bqkv[i] = bq[i];
        else if (i < 1536) bqkv[i] = bk[i - 768];
        else if (i < 2304) bqkv[i] = bv[i - 1536];
        return;
    }
    const float* src; bf16_t* dst; int R, Cc, local;
    if (t < 2304) {
        int which = t / 576; local = t - which * 576;
        src = which == 0 ? wq : (which == 1 ? wk : (which == 2 ? wv : wo));
        dst = which == 3 ? woT : wqkvT + which * 768 * 768;
        R = 768; Cc = 768;
    } else if (t < 4608) { local = t - 2304; src = w1; dst = w1T; R = 768;  Cc = 3072; }
    else                 { local = t - 4608; src = w2; dst = w2T; R = 3072; Cc = 768;  }
    const int ntx = Cc >> 5;
    const int bx = local % ntx, by = local / ntx;
    __shared__ float tile[32][33];
    const int tx = threadIdx.x & 31, ty = threadIdx.x >> 5;
    const int c0 = bx * 32, r0 = by * 32;
    #pragma unroll
    for (int i = 0; i < 32; i += 8)
        tile[ty + i][tx] = src[(size_t)(r0 + ty + i) * Cc + c0 + tx];
    __syncthreads();
    #pragma unroll
    for (int i = 0; i < 32; i += 8)
        dst[(size_t)(c0 + ty + i) * R + r0 + tx] = (bf16_t)tile[tx][ty + i];
}

// ---------------- LayerNorm, coalesced: per block, one [768][16-pixel] f32 tile in LDS
#define LNP 16
#define LNSTRIPS 13            // ceil(196/16)
__global__ __launch_bounds__(256)
void ln_kernel(const float* __restrict__ x, const float* __restrict__ g,
               const float* __restrict__ b, bf16_t* __restrict__ t) {
    __shared__ float tile[C_DIM][LNP + 1];       // 52,224 B; +1 pad (17 coprime 32)
    const int bb = blockIdx.x / LNSTRIPS, s = blockIdx.x % LNSTRIPS;
    const int p0 = s * LNP;
    const int npix = (NPIX - p0) < LNP ? (NPIX - p0) : LNP;   // 16 or 4
    const int tid = threadIdx.x;
    const int pl = tid & 15, c0 = tid >> 4;      // coalesced: 16 lanes = 64B along pixels
    const float* xb = x + (size_t)bb * C_DIM * NPIX;
    if (pl < npix) {
        #pragma unroll
        for (int i = 0; i < 48; ++i) {
            int c = c0 + 16 * i;
            tile[c][pl] = xb[(size_t)c * NPIX + p0 + pl];
        }
    }
    __syncthreads();
    const int wave = tid >> 6, lane = tid & 63;
    #pragma unroll
    for (int pp = 0; pp < 4; ++pp) {
        int p = wave * 4 + pp;
        if (p >= npix) break;
        float vals[12], s1 = 0.f, s2 = 0.f;
        #pragma unroll
        for (int j = 0; j < 12; ++j) {
            float v = tile[lane + 64 * j][p];
            vals[j] = v; s1 += v; s2 += v * v;
        }
        #pragma unroll
        for (int m = 32; m; m >>= 1) { s1 += __shfl_xor(s1, m); s2 += __shfl_xor(s2, m); }
        const float mu = s1 * (1.f / 768.f);
        const float var = s2 * (1.f / 768.f) - mu * mu;
        const float rs = rsqrtf(var + 1e-5f);
        bf16_t* tp = t + (size_t)(bb * NPIX + p0 + p) * C_DIM;
        #pragma unroll
        for (int j = 0; j < 12; ++j) {
            int c = lane + 64 * j;
            tp[c] = (bf16_t)((vals[j] - mu) * rs * g[c] + b[c]);
        }
    }
}

// ---------------- GEMM: C[M][Nn] = A[M][K] * Bt[Nn][K]^T, bf16 in, f32 acc
// 2-phase prefetch (T3-minimal): STAGE(t+1) -> compute(t) -> syncthreads (vmcnt0+bar)
// MODE 0: QKV scatter (+bias)   MODE 1: proj (+bo +x residual -> y1f32_bchw, y1bf16)
// MODE 2: MLP1 (+b1, GELU -> h1 bf16)   MODE 3: MLP2 (+b2 +y1 -> d_out f32 bchw)
#define BM 128
#define BN 128
#define BK 64
#define BUFSZ ((BM + BN) * BK * 2)   // 32 KB per stage buffer

template<int MODE>
__global__ __launch_bounds__(256)
void gemm_k(const bf16_t* __restrict__ A, const bf16_t* __restrict__ Bt,
            int M, int Nn, int K,
            const float* __restrict__ bias,
            const float* __restrict__ aux0, float* __restrict__ aux1,
            bf16_t* __restrict__ ob0, bf16_t* __restrict__ ob1, bf16_t* __restrict__ ob2)
{
    __shared__ __align__(16) char smem[2][BUFSZ];             // 64 KB double-buffer
    const int tid = threadIdx.x;
    const int wave = tid >> 6, lane = tid & 63;
    const int lr = lane & 15, lq = lane >> 4;

    // XCD-chunked bijective swizzle (m204): same-A-panel blocks -> same XCD chunk.
    const int nwg = gridDim.x;
    const int orig = blockIdx.x;
    const int q8 = nwg >> 3, r8 = nwg & 7;
    const int xcd = orig & 7, slot = orig >> 3;
    const int lg = (xcd < r8 ? xcd * (q8 + 1) : r8 * (q8 + 1) + (xcd - r8) * q8) + slot;
    const int gn = Nn >> 7;
    const int nb = lg % gn, mb = lg / gn;
    const int n0 = nb * BN, m0 = mb * BM;

    const int wr = (wave >> 1) * 64, wc = (wave & 1) * 64;
    const int srow = tid >> 3;                               // 0..31
    const int skx = (((tid & 7) ^ (srow & 7)) << 3);         // swizzled k-slot (elements)

    auto stage = [&](char* base, int k0) {
        #pragma unroll
        for (int it = 0; it < 4; ++it) {
            int row = it * 32 + srow;
            async_copy16(A + (size_t)(m0 + row) * K + (k0 + skx),
                         base + ((it * 256 + wave * 64) << 4));
        }
        char* Bb = base + BM * BK * 2;
        #pragma unroll
        for (int it = 0; it < 4; ++it) {
            int row = it * 32 + srow;
            async_copy16(Bt + (size_t)(n0 + row) * K + (k0 + skx),
                         Bb + ((it * 256 + wave * 64) << 4));
        }
    };

    f32x4 acc[4][4];
    #pragma unroll
    for (int i = 0; i < 4; ++i)
        #pragma unroll
        for (int j = 0; j < 4; ++j)
            acc[i][j] = f32x4{0.f, 0.f, 0.f, 0.f};

    stage(smem[0], 0);
    __syncthreads();
    const int nt = K / BK;
    for (int t = 0; t < nt; ++t) {
        char* curb = smem[t & 1];
        if (t + 1 < nt) stage(smem[(t + 1) & 1], (t + 1) * BK);
        char* As = curb;
        char* Bs = curb + BM * BK * 2;
        #pragma unroll
        for (int ks = 0; ks < 2; ++ks) {
            bf16x8 af[4], bfv[4];
            #pragma unroll
            for (int i = 0; i < 4; ++i) {
                int row = wr + i * 16 + lr;
                int inner = (ks * 64 + lq * 16) ^ ((row & 7) << 4);
                af[i] = *(const bf16x8*)(As + row * 128 + inner);
            }
            #pragma unroll
            for (int j = 0; j < 4; ++j) {
                int row = wc + j * 16 + lr;
                int inner = (ks * 64 + lq * 16) ^ ((row & 7) << 4);
                bfv[j] = *(const bf16x8*)(Bs + row * 128 + inner);
            }
            #pragma unroll
            for (int i = 0; i < 4; ++i)
                #pragma unroll
                for (int j = 0; j < 4; ++j)
                    acc[i][j] = mfma16(af[i], bfv[j], acc[i][j]);
        }
        __syncthreads();   // = vmcnt(0) lgkmcnt(0) + barrier: next tile ready, reads done
    }

    // ---- epilogues. C/D layout: col = lane&15 (n), row = lq*4 + reg (m).
    if constexpr (MODE == 0) {          // QKV scatter: q/k/v [b][head][n][d] bf16
        #pragma unroll
        for (int i = 0; i < 4; ++i) {
            const int grow0 = m0 + wr + i * 16 + lq * 4;
            #pragma unroll
            for (int j = 0; j < 4; ++j) {
                const int gcol = n0 + wc + j * 16 + lr;
                const int which = (gcol >= 1536) ? 2 : (gcol >= 768 ? 1 : 0);
                const int rem = gcol - which * 768;
                const int head = rem >> 6, dd = rem & 63;
                bf16_t* dst = which == 0 ? ob0 : (which == 1 ? ob1 : ob2);
                const float bval = bias[gcol];
                #pragma unroll
                for (int r = 0; r < 4; ++r) {
                    int grow = grow0 + r;
                    int bb = grow / NPIX, pix = grow - bb * NPIX;
                    dst[((size_t)(bb * HEADS + head) * NPIX + pix) * 64 + dd] =
                        (bf16_t)(acc[i][j][r] + bval);
                }
            }
        }
    } else if constexpr (MODE == 1) {   // proj: + bo + x -> y1 f32 bchw (aux1), y1 bf16 (ob0)
        #pragma unroll
        for (int i = 0; i < 4; ++i) {
            const int grow0 = m0 + wr + i * 16 + lq * 4;
            const int bb = grow0 / NPIX, pix0 = grow0 - bb * NPIX;
            #pragma unroll
            for (int j = 0; j < 4; ++j) {
                const int gcol = n0 + wc + j * 16 + lr;
                const float bval = bias[gcol];
                if (pix0 <= NPIX - 4) {
                    const size_t base = ((size_t)bb * C_DIM + gcol) * NPIX + pix0;
                    float4 xv = *(const float4*)(aux0 + base);
                    float o0 = acc[i][j][0] + bval + xv.x;
                    float o1 = acc[i][j][1] + bval + xv.y;
                    float o2 = acc[i][j][2] + bval + xv.z;
                    float o3 = acc[i][j][3] + bval + xv.w;
                    float4 ov; ov.x = o0; ov.y = o1; ov.z = o2; ov.w = o3;
                    *(float4*)(aux1 + base) = ov;
                    bf16_t* ob = ob0 + (size_t)grow0 * Nn + gcol;
                    ob[0] = (bf16_t)o0; ob[(size_t)Nn] = (bf16_t)o1;
                    ob[(size_t)2 * Nn] = (bf16_t)o2; ob[(size_t)3 * Nn] = (bf16_t)o3;
                } else {
                    #pragma unroll
                    for (int r = 0; r < 4; ++r) {
                        int grow = grow0 + r;
                        int b3 = grow / NPIX, pix = grow - b3 * NPIX;
                        size_t idx = ((size_t)b3 * C_DIM + gcol) * NPIX + pix;
                        float o = acc[i][j][r] + bval + aux0[idx];
                        aux1[idx] = o;
                        ob0[(size_t)grow * Nn + gcol] = (bf16_t)o;
                    }
                }
            }
        }
    } else if constexpr (MODE == 2) {   // MLP1: + b1, exact GELU -> h1 bf16
        #pragma unroll
        for (int i = 0; i < 4; ++i) {
            const int grow0 = m0 + wr + i * 16 + lq * 4;
            #pragma unroll
            for (int j = 0; j < 4; ++j) {
                const int gcol = n0 + wc + j * 16 + lr;
                const float bval = bias[gcol];
                #pragma unroll
                for (int r = 0; r < 4; ++r) {
                    float v = acc[i][j][r] + bval;
                    float ge = 0.5f * v * (1.f + erff(v * 0.70710678118654752f));
                    ob0[(size_t)(grow0 + r) * Nn + gcol] = (bf16_t)ge;
                }
            }
        }
    } else {                            // MLP2: + b2 + y1(aux0) -> d_out(aux1) f32 bchw
        #pragma unroll
        for (int i = 0; i < 4; ++i) {
            const int grow0 = m0 + wr + i * 16 + lq * 4;
            const int bb = grow0 / NPIX, pix0 = grow0 - bb * NPIX;
            #pragma unroll
            for (int j = 0; j < 4; ++j) {
                const int gcol = n0 + wc + j * 16 + lr;
                const float bval = bias[gcol];
                if (pix0 <= NPIX - 4) {
                    const size_t base = ((size_t)bb * C_DIM + gcol) * NPIX + pix0;
                    float4 yv = *(const float4*)(aux0 + base);
                    float4 ov;
                    ov.x = acc[i][j][0] + bval + yv.x;
                    ov.y = acc[i][j][1] + bval + yv.y;
                    ov.z = acc[i][j][2] + bval + yv.z;
                    ov.w = acc[i][j][3] + bval + yv.w;
                    *(float4*)(aux1 + base) = ov;
                } else {
                    #pragma unroll
                    for (int r = 0; r < 4; ++r) {
                        int grow = grow0 + r;
                        int b3 = grow / NPIX, pix = grow - b3 * NPIX;
                        size_t idx = ((size_t)b3 * C_DIM + gcol) * NPIX + pix;
                        aux1[idx] = acc[i][j][r] + bval + aux0[idx];
                    }
                }
            }
        }
    }
}

// ---------------- attention: one block (256 thr / 4 waves) per (b, head)
__global__ __launch_bounds__(256)
void attn_kernel(const bf16_t* __restrict__ q, const bf16_t* __restrict__ k,
                 const bf16_t* __restrict__ v, const float* __restrict__ rel_bias,
                 bf16_t* __restrict__ out)   // out: [b*196][768] bf16
{
    __shared__ __align__(16) bf16_t VT[64][232];
    __shared__ __align__(16) bf16_t P[4][16][256];
    __shared__ float btab[736];
    const int tid = threadIdx.x, wave = tid >> 6, lane = tid & 63;
    const int lr = lane & 15, lq = lane >> 4;
    const int bh = blockIdx.x;
    const int bb = bh / HEADS, hh = bh - bb * HEADS;

    for (int i = tid; i < 729; i += 256) btab[i] = rel_bias[hh * 729 + i];
    const bf16_t* vbase = v + (size_t)bh * NPIX * 64;
    for (int idx = tid; idx < NPIX * 64; idx += 256)
        VT[idx & 63][idx >> 6] = vbase[idx];
    for (int idx = tid; idx < 64 * 28; idx += 256)
        VT[idx & 63][NPIX + (idx >> 6)] = (bf16_t)0.f;
    {
        int row = lr;
        #pragma unroll
        for (int cc = 0; cc < 4; ++cc) {
            int col = 208 + lq + cc * 4;
            int slot = (col >> 3) ^ (row & 7);
            P[wave][row][slot * 8 + (col & 7)] = (bf16_t)0.f;
        }
    }
    __syncthreads();

    const bf16_t* qb = q + (size_t)bh * NPIX * 64;
    const bf16_t* kb = k + (size_t)bh * NPIX * 64;

    for (int rt = wave; rt < 13; rt += 4) {
        bf16x8 qf0 = *(const bf16x8*)(qb + (rt * 16 + lr) * 64 + lq * 8);
        bf16x8 qf1 = *(const bf16x8*)(qb + (rt * 16 + lr) * 64 + 32 + lq * 8);
        f32x4 acc[13];
        const int nrow0 = rt * 16 + lq * 4;
        #pragma unroll
        for (int ct = 0; ct < 13; ++ct) {
            #pragma unroll
            for (int r = 0; r < 4; ++r) {
                const int n = nrow0 + r;
                const int m = ct * 16 + lr;
                float init;
                if (m < NPIX) {
                    int pyn = n / 14, pxn = n - pyn * 14;
                    int pym = m / 14, pxm = m - pym * 14;
                    init = btab[(pym - pyn + 14) * 14 + (pxm - pxn + 14)];
                } else init = -1e30f;
                acc[ct][r] = init;
            }
        }
        #pragma unroll
        for (int ct = 0; ct < 13; ++ct) {
            const bf16_t* kr = kb + (ct * 16 + lr) * 64 + lq * 8;
            bf16x8 kf0 = *(const bf16x8*)(kr);
            bf16x8 kf1 = *(const bf16x8*)(kr + 32);
            acc[ct] = mfma16(qf0, kf0, acc[ct]);
            acc[ct] = mfma16(qf1, kf1, acc[ct]);
        }
        #pragma unroll
        for (int r = 0; r < 4; ++r) {
            float mx = -1e30f;
            #pragma unroll
            for (int ct = 0; ct < 13; ++ct) mx = fmaxf(mx, acc[ct][r]);
            #pragma unroll
            for (int s = 1; s < 16; s <<= 1) mx = fmaxf(mx, __shfl_xor(mx, s));
            float sum = 0.f;
            #pragma unroll
            for (int ct = 0; ct < 13; ++ct) {
                float e = __expf(acc[ct][r] - mx);
                acc[ct][r] = e; sum += e;
            }
            #pragma unroll
            for (int s = 1; s < 16; s <<= 1) sum += __shfl_xor(sum, s);
            float inv = 1.f / sum;
            #pragma unroll
            for (int ct = 0; ct < 13; ++ct) acc[ct][r] *= inv;
        }
        #pragma unroll
        for (int ct = 0; ct < 13; ++ct) {
            #pragma unroll
            for (int r = 0; r < 4; ++r) {
                int row = lq * 4 + r;
                int col = ct * 16 + lr;
                int slot = (col >> 3) ^ (row & 7);
                P[wave][row][slot * 8 + (col & 7)] = (bf16_t)acc[ct][r];
            }
        }
        f32x4 accO[4];
        #pragma unroll
        for (int dt = 0; dt < 4; ++dt) accO[dt] = f32x4{0.f, 0.f, 0.f, 0.f};
        #pragma unroll
        for (int ks = 0; ks < 7; ++ks) {
            int kk = ks * 32 + lq * 8;
            int slot = (kk >> 3) ^ (lr & 7);
            bf16x8 pa = *(const bf16x8*)(&P[wave][lr][slot * 8]);
            #pragma unroll
            for (int dt = 0; dt < 4; ++dt) {
                bf16x8 vb2 = *(const bf16x8*)(&VT[dt * 16 + lr][kk]);
                accO[dt] = mfma16(pa, vb2, accO[dt]);
            }
        }
        #pragma unroll
        for (int dt = 0; dt < 4; ++dt) {
            #pragma unroll
            for (int r = 0; r < 4; ++r) {
                int n = nrow0 + r;
                if (n < NPIX)
                    out[((size_t)bb * NPIX + n) * C_DIM + hh * 64 + dt * 16 + lr] =
                        (bf16_t)accO[dt][r];
            }
        }
    }
}

extern "C" void kernel_launch(void* const* d_in, const int* in_sizes, int n_in,
                              void* d_out, int out_size, void* d_ws, size_t ws_size,
                              hipStream_t stream) {
    const float* x    = (const float*)d_in[0];
    const float* ln_g = (const float*)d_in[1];
    const float* ln_b = (const float*)d_in[2];
    const float* wq   = (const float*)d_in[3];
    const float* bq   = (const float*)d_in[4];
    const float* wk   = (const float*)d_in[5];
    const float* bk   = (const float*)d_in[6];
    const float* wv   = (const float*)d_in[7];
    const float* bv   = (const float*)d_in[8];
    const float* wo   = (const float*)d_in[9];
    const float* bo   = (const float*)d_in[10];
    const float* w1   = (const float*)d_in[11];
    const float* b1   = (const float*)d_in[12];
    const float* w2   = (const float*)d_in[13];
    const float* b2   = (const float*)d_in[14];
    const float* rb   = (const float*)d_in[15];

    char* ws = (char*)d_ws;
    size_t off = 0;
    auto carve = [&](size_t bytes) -> char* {
        char* p = ws + off;
        off += (bytes + 255) & ~(size_t)255;
        return p;
    };
    const size_t SZROW = (size_t)MTOT * C_DIM * 2;            // 19,267,584 B
    bf16_t* wqkvT = (bf16_t*)carve((size_t)2304 * 768 * 2);
    bf16_t* woT   = (bf16_t*)carve((size_t)768 * 768 * 2);
    bf16_t* w1T   = (bf16_t*)carve((size_t)3072 * 768 * 2);
    bf16_t* w2T   = (bf16_t*)carve((size_t)768 * 3072 * 2);
    float*  bqkv  = (float*)carve(2304 * 4);
    char*   regionA = carve(4 * SZROW + 65536);               // t|q|k|v, reused as h1
    bf16_t* tbuf = (bf16_t*)regionA;
    bf16_t* qb   = (bf16_t*)(regionA + SZROW);
    bf16_t* kb   = (bf16_t*)(regionA + 2 * SZROW);
    bf16_t* vb   = (bf16_t*)(regionA + 3 * SZROW);
    bf16_t* attn_out = tbuf;                                  // t dead after QKV
    bf16_t* h1 = (bf16_t*)regionA;                            // whole region dead after proj
    float*  y1f = (float*)carve((size_t)MTOT * C_DIM * 4);
    bf16_t* y1b = (bf16_t*)carve(SZROW);

    prep_kernel<<<6921, 256, 0, stream>>>(wq, wk, wv, wo, w1, w2, bq, bk, bv,
                                          wqkvT, woT, w1T, w2T, bqkv);
    ln_kernel<<<BATCH * LNSTRIPS, 256, 0, stream>>>(x, ln_g, ln_b, tbuf);
    gemm_k<0><<<18 * 98, 256, 0, stream>>>(tbuf, wqkvT, MTOT, 2304, 768, bqkv,
                                           nullptr, nullptr, qb, kb, vb);
    attn_kernel<<<768, 256, 0, stream>>>(qb, kb, vb, rb, attn_out);
    gemm_k<1><<<6 * 98, 256, 0, stream>>>(attn_out, woT, MTOT, 768, 768, bo,
                                          x, y1f, y1b, nullptr, nullptr);
    gemm_k<2><<<24 * 98, 256, 0, stream>>>(y1b, w1T, MTOT, 3072, 768, b1,
                                           nullptr, nullptr, h1, nullptr, nullptr);
    gemm_k<3><<<6 * 98, 256, 0, stream>>>(h1, w2T, MTOT, 768, 3072, b2,
                                          y1f, (float*)d_out, nullptr, nullptr, nullptr);
}